// Round 4
// baseline (327.771 us; speedup 1.0000x reference)
//
#include <hip/hip_runtime.h>

// EdgeGAT on MI355X — round 13b: DPP butterfly reduce in node_fused (no DS-pipe
// shuffles in the edge loop) + exp2f with log2e folded into attn. Keeps
// round 12's depth-2 gather pipeline, single-atomic-pass prep, atomic-free
// scatter, GEMM-first sg_fused, split fni/fhv layouts.
// (13 -> 13b: dpp ctrl as template parameter — builtin needs constant int.)
//
//   memset counts; prep: cast | BcatT | wsum | pos-histogram (posArr)
//   scan_block_sums + scan_final(self-prefix)  -> rowptr
//   sg_fused: blocks [0, gemmB) = 128x128 dbuf global_load_lds GEMM;
//             blocks [gemmB, ..) = atomic-free edge scatter
//   layouts:
//     fni[n][c]            c = h*64+o, plain         (bias folded in)
//     fnj[n][c]            plain
//     fhv[n][(h*16+(o&15))*4 + (o>>4)]  head-aligned (lane l16 = o&15, m = o>>4)
//   node_fused: per edge: two 8B gathers + logit + 4 DPP-add (VALU butterfly
//     over 16 lanes: quad_perm xor1, xor2, row_ror:4, row_ror:8) + v_exp +
//     4 fma. Once per node: /dsum, cross-quad shfl, coalesced store.

typedef unsigned short ushort_t;
typedef __attribute__((ext_vector_type(8))) short frag_t;     // 8 bf16 (4 VGPRs)
typedef __attribute__((ext_vector_type(4))) float f32x4;
typedef unsigned long long u64_t;

#define CSTRIDE 16   // one counter per 64B line: 16 atomics/line instead of 256

__device__ __forceinline__ ushort_t f2bf(float f) {
    unsigned u = __float_as_uint(f);
    unsigned r = u + 0x7fffu + ((u >> 16) & 1u);   // round-to-nearest-even
    return (ushort_t)(r >> 16);
}
__device__ __forceinline__ float bf2f(ushort_t v) {
    return __uint_as_float(((unsigned)v) << 16);
}
__device__ __forceinline__ float2 bfx2(unsigned u) {   // packed [lo,hi] bf16 -> float2
    float2 f;
    f.x = __uint_as_float(u << 16);
    f.y = __uint_as_float(u & 0xffff0000u);
    return f;
}

// VALU butterfly step: v += dpp_shuffled(v). CTRL: 0xB1=xor1 (quad_perm
// 1,0,3,2), 0x4E=xor2 (quad_perm 2,3,0,1), 0x124=row_ror:4, 0x128=row_ror:8
// (rows are 16 lanes on CDNA). CTRL must be a compile-time constant.
template <int CTRL>
__device__ __forceinline__ float dpp_add(float v) {
    int s = __builtin_amdgcn_update_dpp(0, __float_as_int(v), CTRL, 0xF, 0xF, true);
    return v + __int_as_float(s);
}

// async 16B global->LDS
__device__ __forceinline__ void async_load16(const void* g, void* l) {
    __builtin_amdgcn_global_load_lds(
        (const __attribute__((address_space(1))) unsigned int*)g,
        (__attribute__((address_space(3))) unsigned int*)(unsigned int)(uintptr_t)l,
        16, 0, 0);
}

// ---- fused prep: cast | bcatT | wsum | pos-histogram ------------------------
__global__ __launch_bounds__(256) void prep_kernel(
    const float* __restrict__ nfeats, const float* __restrict__ Wni,
    const float* __restrict__ Wnj, const float* __restrict__ Wnode,
    const float* __restrict__ Wfij, const int* __restrict__ dst,
    ushort_t* __restrict__ Abf, ushort_t* __restrict__ BcatT,
    float* __restrict__ wsum, int* __restrict__ counts,
    int* __restrict__ posArr,
    int castB, int countB, int total4, int E) {
    int b = blockIdx.x;
    int t = threadIdx.x;
    if (b < castB) {                       // cast nfeats: 4x float4 per thread
#pragma unroll
        for (int cc = 0; cc < 4; ++cc) {
            int i = (b * 4 + cc) * 256 + t;
            if (i >= total4) break;
            float4 v = *(const float4*)(nfeats + (size_t)i * 4);
            ushort4 o;
            o.x = f2bf(v.x); o.y = f2bf(v.y); o.z = f2bf(v.z); o.w = f2bf(v.w);
            *(ushort4*)(Abf + (size_t)i * 4) = o;
        }
    } else if (b < castB + 768) {          // BcatT[j][k]
        int j = b - castB;
        int seg = j >> 8;
        const float* W = (seg == 0) ? Wni : (seg == 1) ? Wnj : Wnode;
        BcatT[(size_t)j * 256 + t] = f2bf(W[(size_t)t * 256 + (j & 255)]);
    } else if (b < castB + 768 + countB) { // pos-histogram: one atomic pass
        int i = (b - castB - 768) * 256 + t;
        if (i < E)
            posArr[i] = atomicAdd(&counts[(size_t)dst[i] * CSTRIDE], 1);
    } else {                               // wsum
        float s = 0.f;
#pragma unroll
        for (int k = 0; k < 32; ++k) s += Wfij[k * 256 + t];
        wsum[t] = s;
    }
}

// ---- scans ------------------------------------------------------------------

__global__ __launch_bounds__(256) void scan_block_sums(const int* __restrict__ counts,
                                                       int* __restrict__ bsum, int N) {
    __shared__ int sm[256];
    int i = blockIdx.x * 256 + threadIdx.x;
    sm[threadIdx.x] = (i < N) ? counts[(size_t)i * CSTRIDE] : 0;
    __syncthreads();
#pragma unroll
    for (int off = 128; off; off >>= 1) {
        if (threadIdx.x < off) sm[threadIdx.x] += sm[threadIdx.x + off];
        __syncthreads();
    }
    if (threadIdx.x == 0) bsum[blockIdx.x] = sm[0];
}

__global__ __launch_bounds__(256) void scan_final(const int* __restrict__ counts,
                                                  const int* __restrict__ bsum,
                                                  int* __restrict__ rowptr,
                                                  int N, int E) {
    __shared__ int sm[256];
    __shared__ int smp[256];
    int t = threadIdx.x;
    int b = blockIdx.x;
    int i = b * 256 + t;

    smp[t] = (t < b) ? bsum[t] : 0;
    int c = (i < N) ? counts[(size_t)i * CSTRIDE] : 0;
    sm[t] = c;
    __syncthreads();
#pragma unroll
    for (int off = 128; off; off >>= 1) {
        if (t < off) smp[t] += smp[t + off];
        __syncthreads();
    }
    int prefix = smp[0];
    for (int off = 1; off < 256; off <<= 1) {
        int v = (t >= off) ? sm[t - off] : 0;
        __syncthreads();
        sm[t] += v;
        __syncthreads();
    }
    int ex = prefix + sm[t] - c;
    if (i < N) rowptr[i] = ex;
    if (i == 0) rowptr[N] = E;
}

// ---- fused MFMA GEMM + atomic-free scatter ----------------------------------
// blocks [0, gemmB): gemm, flattened (row-block = bx % gX, col-block = bx / gX).
// blocks [gemmB, gemmB+scatB): edge scatter (fills CUs as gemm blocks retire).
__global__ __launch_bounds__(256) void sg_fused(
    // scatter args
    const int* __restrict__ src, const int* __restrict__ dst,
    const float* __restrict__ reward, const int* __restrict__ rowptr,
    const int* __restrict__ posArr, u64_t* __restrict__ epair, int E, int gemmB,
    // gemm args
    const ushort_t* __restrict__ A, const ushort_t* __restrict__ BT,
    const float* __restrict__ bias, ushort_t* __restrict__ fni,
    ushort_t* __restrict__ fhv, ushort_t* __restrict__ fnj, int N, int gX) {
    __shared__ ushort_t As[2][128][32];
    __shared__ ushort_t Bs[2][128][32];

    if ((int)blockIdx.x >= gemmB) {
        int i = ((int)blockIdx.x - gemmB) * 256 + threadIdx.x;
        if (i < E) {
            int d = dst[i];
            int pos = rowptr[d] + posArr[i];
            epair[pos] = ((u64_t)__float_as_uint(reward[i]) << 32) | (unsigned)src[i];
        }
        return;
    }

    const int bx = blockIdx.x;
    const int brow = bx % gX;
    const int bcol = bx / gX;

    const int tid = threadIdx.x;
    const int wave = tid >> 6, lane = tid & 63;
    const int quad = lane >> 4, l16 = lane & 15;
    const int wr = wave & 1, wc = wave >> 1;
    const int row0 = brow * 128;
    const int col0 = bcol * 128;               // 0..640
    const int Nm1 = N - 1;
    const int srow = lane >> 2;
    const int skof = (lane & 3) * 8;

    f32x4 acc[4][4] = {};

#pragma unroll
    for (int j = 0; j < 2; ++j) {
        int r = wave * 32 + j * 16 + srow;
        int grow = row0 + r; if (grow > Nm1) grow = Nm1;
        async_load16(A + (size_t)grow * 256 + skof, &As[0][wave * 32 + j * 16][0]);
        async_load16(BT + (size_t)(col0 + r) * 256 + skof, &Bs[0][wave * 32 + j * 16][0]);
    }

    for (int it = 0; it < 8; ++it) {
        const int cur = it & 1;
        __syncthreads();
        if (it < 7) {
            const int k1 = (it + 1) * 32;
#pragma unroll
            for (int j = 0; j < 2; ++j) {
                int r = wave * 32 + j * 16 + srow;
                int grow = row0 + r; if (grow > Nm1) grow = Nm1;
                async_load16(A + (size_t)grow * 256 + k1 + skof,
                             &As[1 - cur][wave * 32 + j * 16][0]);
                async_load16(BT + (size_t)(col0 + r) * 256 + k1 + skof,
                             &Bs[1 - cur][wave * 32 + j * 16][0]);
            }
        }

        frag_t af[4], bfr[4];
#pragma unroll
        for (int i = 0; i < 4; ++i)
            af[i] = *(const frag_t*)&As[cur][wr * 64 + i * 16 + l16][quad * 8];
#pragma unroll
        for (int j = 0; j < 4; ++j)
            bfr[j] = *(const frag_t*)&Bs[cur][wc * 64 + j * 16 + l16][quad * 8];

#pragma unroll
        for (int i = 0; i < 4; ++i)
#pragma unroll
            for (int j = 0; j < 4; ++j)
                acc[i][j] = __builtin_amdgcn_mfma_f32_16x16x32_bf16(af[i], bfr[j], acc[i][j], 0, 0, 0);
    }

    // epilogue: split layouts; every 64B line written wholly by this block
#pragma unroll
    for (int i = 0; i < 4; ++i) {
#pragma unroll
        for (int j = 0; j < 4; ++j) {
#pragma unroll
            for (int r = 0; r < 4; ++r) {
                int row = row0 + wr * 64 + i * 16 + quad * 4 + r;
                if (row >= N) continue;
                int col = col0 + wc * 64 + j * 16 + l16;
                float v = acc[i][j][r];
                if (col < 256) {
                    fni[(size_t)row * 256 + col] = f2bf(v + bias[col]);
                } else if (col < 512) {
                    fnj[(size_t)row * 256 + (col - 256)] = f2bf(v);
                } else {
                    int c2 = col - 512;   // h = c2>>6, o = c2&63
                    int h = c2 >> 6, o = c2 & 63;
                    fhv[(size_t)row * 256 + ((h * 16 + (o & 15)) << 2) + (o >> 4)] =
                        f2bf(v);
                }
            }
        }
    }
}

// ---- fused per-node edge phase (DPP butterfly, depth-2 gathers) -------------

__global__ __launch_bounds__(256) void node_fused(
    const ushort_t* __restrict__ fni, const ushort_t* __restrict__ fhv,
    const ushort_t* __restrict__ fnj,
    const int* __restrict__ rowptr, const u64_t* __restrict__ epair,
    const float* __restrict__ wsum, const float* __restrict__ attn,
    float* __restrict__ out, int N) {
    int node = (int)((blockIdx.x * (size_t)blockDim.x + threadIdx.x) >> 6);
    int lane = threadIdx.x & 63;
    if (node >= N) return;

    int base = rowptr[node], end = rowptr[node + 1];
    int j0 = lane * 4;
    if (base >= end) { out[(size_t)node * 64 + lane] = 0.f; return; }

    float4 ws = *(const float4*)(wsum + j0);
    float4 at = *(const float4*)(attn + j0);
    // fold log2(e) into attn: exp(dot) == exp2(dot * log2e) == v_exp_f32
    const float L2E = 1.44269504088896f;
    at.x *= L2E; at.y *= L2E; at.z *= L2E; at.w *= L2E;
    ushort4 njv = *(const ushort4*)(fnj + (size_t)node * 256 + j0);
    float nj0 = bf2f(njv.x), nj1 = bf2f(njv.y), nj2 = bf2f(njv.z), nj3 = bf2f(njv.w);

    float a0 = 0.f, a1 = 0.f, a2 = 0.f, a3 = 0.f, dsum = 0.f;
    const unsigned lo8b = (unsigned)lane * 8u;   // byte offset within 512B row
    const char* fniB = (const char*)fni;
    const char* fhvB = (const char*)fhv;
    const int last = end - 1;

    // epair window: e+0..e+3 (uniform indices -> scalar loads), clamped
    u64_t p0 = epair[base];
    u64_t p1 = epair[min(base + 1, last)];
    u64_t p2 = epair[min(base + 2, last)];
    u64_t p3 = epair[min(base + 3, last)];

    // rows for e0, e1 in flight
    unsigned s0 = (unsigned)__builtin_amdgcn_readfirstlane((int)(unsigned)p0);
    unsigned s1 = (unsigned)__builtin_amdgcn_readfirstlane((int)(unsigned)p1);
    uint2 niA = *(const uint2*)(fniB + (size_t)(s0 * 512u + lo8b));
    uint2 hvA = *(const uint2*)(fhvB + (size_t)(s0 * 512u + lo8b));
    uint2 niB = *(const uint2*)(fniB + (size_t)(s1 * 512u + lo8b));
    uint2 hvB = *(const uint2*)(fhvB + (size_t)(s1 * 512u + lo8b));

    for (int e = base; e < end; e += 2) {
        // issue rows for e+2, e+3 (clamped; tail compute is predicated off)
        unsigned s2 = (unsigned)__builtin_amdgcn_readfirstlane((int)(unsigned)p2);
        unsigned s3 = (unsigned)__builtin_amdgcn_readfirstlane((int)(unsigned)p3);
        uint2 niC = *(const uint2*)(fniB + (size_t)(s2 * 512u + lo8b));
        uint2 hvC = *(const uint2*)(fhvB + (size_t)(s2 * 512u + lo8b));
        uint2 niD = *(const uint2*)(fniB + (size_t)(s3 * 512u + lo8b));
        uint2 hvD = *(const uint2*)(fhvB + (size_t)(s3 * 512u + lo8b));
        // scalar epair prefetch for e+4, e+5
        u64_t p4 = epair[min(e + 4, last)];
        u64_t p5 = epair[min(e + 5, last)];

        // ---- edge e ----
        {
            float r = __uint_as_float(
                __builtin_amdgcn_readfirstlane((int)(unsigned)(p0 >> 32)));
            float2 b01 = bfx2(niA.x), b23 = bfx2(niA.y);
            float x0 = fmaf(r, ws.x, nj0) + b01.x;
            float x1 = fmaf(r, ws.y, nj1) + b01.y;
            float x2 = fmaf(r, ws.z, nj2) + b23.x;
            float x3 = fmaf(r, ws.w, nj3) + b23.y;
            x0 = fmaxf(x0, 0.2f * x0);
            x1 = fmaxf(x1, 0.2f * x1);
            x2 = fmaxf(x2, 0.2f * x2);
            x3 = fmaxf(x3, 0.2f * x3);
            float acc = at.x * x0 + at.y * x1 + at.z * x2 + at.w * x3;
            acc = dpp_add<0xB1>(acc);    // xor1 (quad_perm 1,0,3,2)
            acc = dpp_add<0x4E>(acc);    // xor2 (quad_perm 2,3,0,1)
            acc = dpp_add<0x124>(acc);   // row_ror:4
            acc = dpp_add<0x128>(acc);   // row_ror:8  -> full 16-lane sum
            float eh = exp2f(acc);
            dsum += eh;
            float2 h01 = bfx2(hvA.x), h23 = bfx2(hvA.y);
            a0 = fmaf(eh, h01.x, a0);
            a1 = fmaf(eh, h01.y, a1);
            a2 = fmaf(eh, h23.x, a2);
            a3 = fmaf(eh, h23.y, a3);
        }

        // ---- edge e+1 (predicated: contributes 0 past the tail) ----
        {
            float r = __uint_as_float(
                __builtin_amdgcn_readfirstlane((int)(unsigned)(p1 >> 32)));
            float2 b01 = bfx2(niB.x), b23 = bfx2(niB.y);
            float x0 = fmaf(r, ws.x, nj0) + b01.x;
            float x1 = fmaf(r, ws.y, nj1) + b01.y;
            float x2 = fmaf(r, ws.z, nj2) + b23.x;
            float x3 = fmaf(r, ws.w, nj3) + b23.y;
            x0 = fmaxf(x0, 0.2f * x0);
            x1 = fmaxf(x1, 0.2f * x1);
            x2 = fmaxf(x2, 0.2f * x2);
            x3 = fmaxf(x3, 0.2f * x3);
            float acc = at.x * x0 + at.y * x1 + at.z * x2 + at.w * x3;
            acc = dpp_add<0xB1>(acc);
            acc = dpp_add<0x4E>(acc);
            acc = dpp_add<0x124>(acc);
            acc = dpp_add<0x128>(acc);
            float eh = (e + 1 <= last) ? exp2f(acc) : 0.f;
            dsum += eh;
            float2 h01 = bfx2(hvB.x), h23 = bfx2(hvB.y);
            a0 = fmaf(eh, h01.x, a0);
            a1 = fmaf(eh, h01.y, a1);
            a2 = fmaf(eh, h23.x, a2);
            a3 = fmaf(eh, h23.y, a3);
        }

        p0 = p2; p1 = p3; p2 = p4; p3 = p5;
        niA = niC; hvA = hvC; niB = niD; hvB = hvD;
    }

    // normalize by this head's denom, then sum across quads (heads)
    float inv = __fdividef(0.25f, dsum);
    float v0 = a0 * inv, v1 = a1 * inv, v2 = a2 * inv, v3 = a3 * inv;
    v0 += __shfl_xor(v0, 16, 64); v1 += __shfl_xor(v1, 16, 64);
    v2 += __shfl_xor(v2, 16, 64); v3 += __shfl_xor(v3, 16, 64);
    v0 += __shfl_xor(v0, 32, 64); v1 += __shfl_xor(v1, 32, 64);
    v2 += __shfl_xor(v2, 32, 64); v3 += __shfl_xor(v3, 32, 64);
    // lane writes o = lane: select m = quad (o = l16 + 16*quad)
    int quad = lane >> 4;
    float v = (quad == 0) ? v0 : (quad == 1) ? v1 : (quad == 2) ? v2 : v3;
    out[(size_t)node * 64 + lane] = fmaxf(v, 0.f);
}

// ---- launch -----------------------------------------------------------------

extern "C" void kernel_launch(void* const* d_in, const int* in_sizes, int n_in,
                              void* d_out, int out_size, void* d_ws, size_t ws_size,
                              hipStream_t stream) {
    const float* nfeats = (const float*)d_in[0];
    const float* reward = (const float*)d_in[1];
    const int* src = (const int*)d_in[2];
    const int* dst = (const int*)d_in[3];
    const float* Wni = (const float*)d_in[4];
    const float* Wnj = (const float*)d_in[5];
    const float* Wfij = (const float*)d_in[6];
    const float* Wnode = (const float*)d_in[7];
    const float* bias = (const float*)d_in[8];
    const float* attn = (const float*)d_in[9];
    float* out = (float*)d_out;

    const int N = in_sizes[0] / 256;
    const int E = in_sizes[1];
    const int NB = (N + 255) / 256;       // <= 256 (N <= 65536)
    const int total4 = N * 64;
    const int castB = (total4 + 1023) / 1024;
    const int countB = (E + 255) / 256;

    char* p = (char*)d_ws;
    auto alloc = [&](size_t bytes) { char* r = p; p += (bytes + 63) & ~63ull; return r; };
    u64_t* epair = (u64_t*)alloc((size_t)E * sizeof(u64_t));
    float* wsum = (float*)alloc(256 * sizeof(float));
    int* counts = (int*)alloc((size_t)N * CSTRIDE * sizeof(int));
    int* bsum = (int*)alloc(256 * sizeof(int));
    int* rowptr = (int*)alloc((size_t)(N + 1) * sizeof(int));
    int* posArr = (int*)alloc((size_t)E * sizeof(int));
    ushort_t* fni = (ushort_t*)alloc((size_t)N * 256 * sizeof(ushort_t));
    ushort_t* fhv = (ushort_t*)alloc((size_t)N * 256 * sizeof(ushort_t));
    ushort_t* fnj = (ushort_t*)alloc((size_t)N * 256 * sizeof(ushort_t));
    ushort_t* Abf = (ushort_t*)alloc((size_t)N * 256 * sizeof(ushort_t));
    ushort_t* BcatT = (ushort_t*)alloc((size_t)768 * 256 * sizeof(ushort_t));

    (void)hipMemsetAsync(counts, 0, (size_t)N * CSTRIDE * sizeof(int), stream);

    prep_kernel<<<castB + 768 + countB + 1, 256, 0, stream>>>(
        nfeats, Wni, Wnj, Wnode, Wfij, dst, Abf, BcatT, wsum, counts, posArr,
        castB, countB, total4, E);

    scan_block_sums<<<NB, 256, 0, stream>>>(counts, bsum, N);
    scan_final<<<NB, 256, 0, stream>>>(counts, bsum, rowptr, N, E);

    const int gX = (N + 127) / 128;
    const int gemmB = gX * 6;
    sg_fused<<<gemmB + countB, 256, 0, stream>>>(
        src, dst, reward, rowptr, posArr, epair, E, gemmB,
        Abf, BcatT, bias, fni, fhv, fnj, N, gX);

    node_fused<<<(N + 3) / 4, 256, 0, stream>>>(fni, fhv, fnj, rowptr, epair,
                                                wsum, attn, out, N);
}

// Round 5
// 321.823 us; speedup vs baseline: 1.0185x; 1.0185x over previous
//
#include <hip/hip_runtime.h>

// EdgeGAT on MI355X — round 14: scalarized node_fused. base/end forced into
// SGPRs via readfirstlane => epair prefetches become s_load, row pointers
// become SALU (saddr + lane voffset), r comes from an SGPR hi-word. Depth-4
// row pipeline (8 rows in flight). Keeps DPP butterfly + exp2, single-atomic-
// pass prep, atomic-free scatter, GEMM-first sg_fused, split fni/fhv layouts.
//
//   memset counts; prep: cast | BcatT | wsum | pos-histogram (posArr)
//   scan_block_sums + scan_final(self-prefix)  -> rowptr
//   sg_fused: blocks [0, gemmB) = 128x128 dbuf global_load_lds GEMM;
//             blocks [gemmB, ..) = atomic-free edge scatter
//   layouts:
//     fni[n][c]            c = h*64+o, plain         (bias folded in)
//     fnj[n][c]            plain
//     fhv[n][(h*16+(o&15))*4 + (o>>4)]  head-aligned (lane l16 = o&15, m = o>>4)
//   node_fused: per edge: two 8B saddr-gathers + logit + 4 DPP-add + v_exp +
//     4 fma; all edge bookkeeping on the scalar pipe. Once per node: /dsum,
//     cross-quad shfl, coalesced store.

typedef unsigned short ushort_t;
typedef __attribute__((ext_vector_type(8))) short frag_t;     // 8 bf16 (4 VGPRs)
typedef __attribute__((ext_vector_type(4))) float f32x4;
typedef unsigned long long u64_t;

#define CSTRIDE 16   // one counter per 64B line: 16 atomics/line instead of 256

__device__ __forceinline__ ushort_t f2bf(float f) {
    unsigned u = __float_as_uint(f);
    unsigned r = u + 0x7fffu + ((u >> 16) & 1u);   // round-to-nearest-even
    return (ushort_t)(r >> 16);
}
__device__ __forceinline__ float bf2f(ushort_t v) {
    return __uint_as_float(((unsigned)v) << 16);
}
__device__ __forceinline__ float2 bfx2(unsigned u) {   // packed [lo,hi] bf16 -> float2
    float2 f;
    f.x = __uint_as_float(u << 16);
    f.y = __uint_as_float(u & 0xffff0000u);
    return f;
}

// VALU butterfly step: v += dpp_shuffled(v). CTRL: 0xB1=xor1 (quad_perm
// 1,0,3,2), 0x4E=xor2 (quad_perm 2,3,0,1), 0x124=row_ror:4, 0x128=row_ror:8
// (rows are 16 lanes on CDNA). CTRL must be a compile-time constant.
template <int CTRL>
__device__ __forceinline__ float dpp_add(float v) {
    int s = __builtin_amdgcn_update_dpp(0, __float_as_int(v), CTRL, 0xF, 0xF, true);
    return v + __int_as_float(s);
}

// async 16B global->LDS
__device__ __forceinline__ void async_load16(const void* g, void* l) {
    __builtin_amdgcn_global_load_lds(
        (const __attribute__((address_space(1))) unsigned int*)g,
        (__attribute__((address_space(3))) unsigned int*)(unsigned int)(uintptr_t)l,
        16, 0, 0);
}

// ---- fused prep: cast | bcatT | wsum | pos-histogram ------------------------
__global__ __launch_bounds__(256) void prep_kernel(
    const float* __restrict__ nfeats, const float* __restrict__ Wni,
    const float* __restrict__ Wnj, const float* __restrict__ Wnode,
    const float* __restrict__ Wfij, const int* __restrict__ dst,
    ushort_t* __restrict__ Abf, ushort_t* __restrict__ BcatT,
    float* __restrict__ wsum, int* __restrict__ counts,
    int* __restrict__ posArr,
    int castB, int countB, int total4, int E) {
    int b = blockIdx.x;
    int t = threadIdx.x;
    if (b < castB) {                       // cast nfeats: 4x float4 per thread
#pragma unroll
        for (int cc = 0; cc < 4; ++cc) {
            int i = (b * 4 + cc) * 256 + t;
            if (i >= total4) break;
            float4 v = *(const float4*)(nfeats + (size_t)i * 4);
            ushort4 o;
            o.x = f2bf(v.x); o.y = f2bf(v.y); o.z = f2bf(v.z); o.w = f2bf(v.w);
            *(ushort4*)(Abf + (size_t)i * 4) = o;
        }
    } else if (b < castB + 768) {          // BcatT[j][k]
        int j = b - castB;
        int seg = j >> 8;
        const float* W = (seg == 0) ? Wni : (seg == 1) ? Wnj : Wnode;
        BcatT[(size_t)j * 256 + t] = f2bf(W[(size_t)t * 256 + (j & 255)]);
    } else if (b < castB + 768 + countB) { // pos-histogram: one atomic pass
        int i = (b - castB - 768) * 256 + t;
        if (i < E)
            posArr[i] = atomicAdd(&counts[(size_t)dst[i] * CSTRIDE], 1);
    } else {                               // wsum
        float s = 0.f;
#pragma unroll
        for (int k = 0; k < 32; ++k) s += Wfij[k * 256 + t];
        wsum[t] = s;
    }
}

// ---- scans ------------------------------------------------------------------

__global__ __launch_bounds__(256) void scan_block_sums(const int* __restrict__ counts,
                                                       int* __restrict__ bsum, int N) {
    __shared__ int sm[256];
    int i = blockIdx.x * 256 + threadIdx.x;
    sm[threadIdx.x] = (i < N) ? counts[(size_t)i * CSTRIDE] : 0;
    __syncthreads();
#pragma unroll
    for (int off = 128; off; off >>= 1) {
        if (threadIdx.x < off) sm[threadIdx.x] += sm[threadIdx.x + off];
        __syncthreads();
    }
    if (threadIdx.x == 0) bsum[blockIdx.x] = sm[0];
}

__global__ __launch_bounds__(256) void scan_final(const int* __restrict__ counts,
                                                  const int* __restrict__ bsum,
                                                  int* __restrict__ rowptr,
                                                  int N, int E) {
    __shared__ int sm[256];
    __shared__ int smp[256];
    int t = threadIdx.x;
    int b = blockIdx.x;
    int i = b * 256 + t;

    smp[t] = (t < b) ? bsum[t] : 0;
    int c = (i < N) ? counts[(size_t)i * CSTRIDE] : 0;
    sm[t] = c;
    __syncthreads();
#pragma unroll
    for (int off = 128; off; off >>= 1) {
        if (t < off) smp[t] += smp[t + off];
        __syncthreads();
    }
    int prefix = smp[0];
    for (int off = 1; off < 256; off <<= 1) {
        int v = (t >= off) ? sm[t - off] : 0;
        __syncthreads();
        sm[t] += v;
        __syncthreads();
    }
    int ex = prefix + sm[t] - c;
    if (i < N) rowptr[i] = ex;
    if (i == 0) rowptr[N] = E;
}

// ---- fused MFMA GEMM + atomic-free scatter ----------------------------------
// blocks [0, gemmB): gemm, flattened (row-block = bx % gX, col-block = bx / gX).
// blocks [gemmB, gemmB+scatB): edge scatter (fills CUs as gemm blocks retire).
__global__ __launch_bounds__(256) void sg_fused(
    // scatter args
    const int* __restrict__ src, const int* __restrict__ dst,
    const float* __restrict__ reward, const int* __restrict__ rowptr,
    const int* __restrict__ posArr, u64_t* __restrict__ epair, int E, int gemmB,
    // gemm args
    const ushort_t* __restrict__ A, const ushort_t* __restrict__ BT,
    const float* __restrict__ bias, ushort_t* __restrict__ fni,
    ushort_t* __restrict__ fhv, ushort_t* __restrict__ fnj, int N, int gX) {
    __shared__ ushort_t As[2][128][32];
    __shared__ ushort_t Bs[2][128][32];

    if ((int)blockIdx.x >= gemmB) {
        int i = ((int)blockIdx.x - gemmB) * 256 + threadIdx.x;
        if (i < E) {
            int d = dst[i];
            int pos = rowptr[d] + posArr[i];
            epair[pos] = ((u64_t)__float_as_uint(reward[i]) << 32) | (unsigned)src[i];
        }
        return;
    }

    const int bx = blockIdx.x;
    const int brow = bx % gX;
    const int bcol = bx / gX;

    const int tid = threadIdx.x;
    const int wave = tid >> 6, lane = tid & 63;
    const int quad = lane >> 4, l16 = lane & 15;
    const int wr = wave & 1, wc = wave >> 1;
    const int row0 = brow * 128;
    const int col0 = bcol * 128;               // 0..640
    const int Nm1 = N - 1;
    const int srow = lane >> 2;
    const int skof = (lane & 3) * 8;

    f32x4 acc[4][4] = {};

#pragma unroll
    for (int j = 0; j < 2; ++j) {
        int r = wave * 32 + j * 16 + srow;
        int grow = row0 + r; if (grow > Nm1) grow = Nm1;
        async_load16(A + (size_t)grow * 256 + skof, &As[0][wave * 32 + j * 16][0]);
        async_load16(BT + (size_t)(col0 + r) * 256 + skof, &Bs[0][wave * 32 + j * 16][0]);
    }

    for (int it = 0; it < 8; ++it) {
        const int cur = it & 1;
        __syncthreads();
        if (it < 7) {
            const int k1 = (it + 1) * 32;
#pragma unroll
            for (int j = 0; j < 2; ++j) {
                int r = wave * 32 + j * 16 + srow;
                int grow = row0 + r; if (grow > Nm1) grow = Nm1;
                async_load16(A + (size_t)grow * 256 + k1 + skof,
                             &As[1 - cur][wave * 32 + j * 16][0]);
                async_load16(BT + (size_t)(col0 + r) * 256 + k1 + skof,
                             &Bs[1 - cur][wave * 32 + j * 16][0]);
            }
        }

        frag_t af[4], bfr[4];
#pragma unroll
        for (int i = 0; i < 4; ++i)
            af[i] = *(const frag_t*)&As[cur][wr * 64 + i * 16 + l16][quad * 8];
#pragma unroll
        for (int j = 0; j < 4; ++j)
            bfr[j] = *(const frag_t*)&Bs[cur][wc * 64 + j * 16 + l16][quad * 8];

#pragma unroll
        for (int i = 0; i < 4; ++i)
#pragma unroll
            for (int j = 0; j < 4; ++j)
                acc[i][j] = __builtin_amdgcn_mfma_f32_16x16x32_bf16(af[i], bfr[j], acc[i][j], 0, 0, 0);
    }

    // epilogue: split layouts; every 64B line written wholly by this block
#pragma unroll
    for (int i = 0; i < 4; ++i) {
#pragma unroll
        for (int j = 0; j < 4; ++j) {
#pragma unroll
            for (int r = 0; r < 4; ++r) {
                int row = row0 + wr * 64 + i * 16 + quad * 4 + r;
                if (row >= N) continue;
                int col = col0 + wc * 64 + j * 16 + l16;
                float v = acc[i][j][r];
                if (col < 256) {
                    fni[(size_t)row * 256 + col] = f2bf(v + bias[col]);
                } else if (col < 512) {
                    fnj[(size_t)row * 256 + (col - 256)] = f2bf(v);
                } else {
                    int c2 = col - 512;   // h = c2>>6, o = c2&63
                    int h = c2 >> 6, o = c2 & 63;
                    fhv[(size_t)row * 256 + ((h * 16 + (o & 15)) << 2) + (o >> 4)] =
                        f2bf(v);
                }
            }
        }
    }
}

// ---- fused per-node edge phase (scalarized bookkeeping, depth-4 gathers) ----

__global__ __launch_bounds__(256) void node_fused(
    const ushort_t* __restrict__ fni, const ushort_t* __restrict__ fhv,
    const ushort_t* __restrict__ fnj,
    const int* __restrict__ rowptr, const u64_t* __restrict__ epair,
    const float* __restrict__ wsum, const float* __restrict__ attn,
    float* __restrict__ out, int N) {
    int node = (int)((blockIdx.x * (size_t)blockDim.x + threadIdx.x) >> 6);
    int lane = threadIdx.x & 63;
    if (node >= N) return;

    // force wave-uniform values into SGPRs: everything derived (epair indices,
    // row bases) compiles to scalar loads / SALU address math.
    const int base = __builtin_amdgcn_readfirstlane(rowptr[node]);
    const int end = __builtin_amdgcn_readfirstlane(rowptr[node + 1]);
    const int j0 = lane * 4;
    if (base >= end) { out[(size_t)node * 64 + lane] = 0.f; return; }

    float4 ws = *(const float4*)(wsum + j0);
    float4 at = *(const float4*)(attn + j0);
    // fold log2(e) into attn: exp(dot) == exp2(dot * log2e) == v_exp_f32
    const float L2E = 1.44269504088896f;
    at.x *= L2E; at.y *= L2E; at.z *= L2E; at.w *= L2E;
    ushort4 njv = *(const ushort4*)(fnj + (size_t)node * 256 + j0);
    float nj0 = bf2f(njv.x), nj1 = bf2f(njv.y), nj2 = bf2f(njv.z), nj3 = bf2f(njv.w);

    float a0 = 0.f, a1 = 0.f, a2 = 0.f, a3 = 0.f, dsum = 0.f;
    const int last = end - 1;

    // uniform row gather: tbl + s*256 is SALU; + j0 is the lane voffset
    auto prow = [&](const ushort_t* tbl, u64_t p) -> uint2 {
        unsigned s = (unsigned)p;
        return *(const uint2*)(tbl + (size_t)s * 256 + j0);
    };

    // edge body: ~40 VALU ops, zero addressing overhead
    auto edge = [&](u64_t p, uint2 ni, uint2 hv, bool live) {
        float r = __uint_as_float((unsigned)(p >> 32));   // SGPR operand
        float2 b01 = bfx2(ni.x), b23 = bfx2(ni.y);
        float x0 = fmaf(r, ws.x, nj0) + b01.x;
        float x1 = fmaf(r, ws.y, nj1) + b01.y;
        float x2 = fmaf(r, ws.z, nj2) + b23.x;
        float x3 = fmaf(r, ws.w, nj3) + b23.y;
        x0 = fmaxf(x0, 0.2f * x0);
        x1 = fmaxf(x1, 0.2f * x1);
        x2 = fmaxf(x2, 0.2f * x2);
        x3 = fmaxf(x3, 0.2f * x3);
        float acc = at.x * x0 + at.y * x1 + at.z * x2 + at.w * x3;
        acc = dpp_add<0xB1>(acc);    // xor1 (quad_perm 1,0,3,2)
        acc = dpp_add<0x4E>(acc);    // xor2 (quad_perm 2,3,0,1)
        acc = dpp_add<0x124>(acc);   // row_ror:4
        acc = dpp_add<0x128>(acc);   // row_ror:8  -> full 16-lane sum
        float eh = live ? exp2f(acc) : 0.f;
        dsum += eh;
        float2 h01 = bfx2(hv.x), h23 = bfx2(hv.y);
        a0 = fmaf(eh, h01.x, a0);
        a1 = fmaf(eh, h01.y, a1);
        a2 = fmaf(eh, h23.x, a2);
        a3 = fmaf(eh, h23.y, a3);
    };

    // epair window e..e+7 (scalar loads), rows for e..e+3 in flight
    u64_t p0 = epair[base];
    u64_t p1 = epair[min(base + 1, last)];
    u64_t p2 = epair[min(base + 2, last)];
    u64_t p3 = epair[min(base + 3, last)];
    u64_t p4 = epair[min(base + 4, last)];
    u64_t p5 = epair[min(base + 5, last)];

    uint2 niA = prow(fni, p0), hvA = prow(fhv, p0);
    uint2 niB = prow(fni, p1), hvB = prow(fhv, p1);
    uint2 niC = prow(fni, p2), hvC = prow(fhv, p2);
    uint2 niD = prow(fni, p3), hvD = prow(fhv, p3);

    for (int e = base; e < end; e += 2) {
        // issue rows for e+4, e+5 (distance-4; clamped tail rows are benign)
        uint2 niE = prow(fni, p4), hvE = prow(fhv, p4);
        uint2 niF = prow(fni, p5), hvF = prow(fhv, p5);
        u64_t p6 = epair[min(e + 6, last)];
        u64_t p7 = epair[min(e + 7, last)];

        edge(p0, niA, hvA, true);
        edge(p1, niB, hvB, e + 1 <= last);

        p0 = p2; p1 = p3; p2 = p4; p3 = p5; p4 = p6; p5 = p7;
        niA = niC; hvA = hvC; niB = niD; hvB = hvD;
        niC = niE; hvC = hvE; niD = niF; hvD = hvF;
    }

    // normalize by this head's denom, then sum across quads (heads)
    float inv = __fdividef(0.25f, dsum);
    float v0 = a0 * inv, v1 = a1 * inv, v2 = a2 * inv, v3 = a3 * inv;
    v0 += __shfl_xor(v0, 16, 64); v1 += __shfl_xor(v1, 16, 64);
    v2 += __shfl_xor(v2, 16, 64); v3 += __shfl_xor(v3, 16, 64);
    v0 += __shfl_xor(v0, 32, 64); v1 += __shfl_xor(v1, 32, 64);
    v2 += __shfl_xor(v2, 32, 64); v3 += __shfl_xor(v3, 32, 64);
    // lane writes o = lane: select m = quad (o = l16 + 16*quad)
    int quad = lane >> 4;
    float v = (quad == 0) ? v0 : (quad == 1) ? v1 : (quad == 2) ? v2 : v3;
    out[(size_t)node * 64 + lane] = fmaxf(v, 0.f);
}

// ---- launch -----------------------------------------------------------------

extern "C" void kernel_launch(void* const* d_in, const int* in_sizes, int n_in,
                              void* d_out, int out_size, void* d_ws, size_t ws_size,
                              hipStream_t stream) {
    const float* nfeats = (const float*)d_in[0];
    const float* reward = (const float*)d_in[1];
    const int* src = (const int*)d_in[2];
    const int* dst = (const int*)d_in[3];
    const float* Wni = (const float*)d_in[4];
    const float* Wnj = (const float*)d_in[5];
    const float* Wfij = (const float*)d_in[6];
    const float* Wnode = (const float*)d_in[7];
    const float* bias = (const float*)d_in[8];
    const float* attn = (const float*)d_in[9];
    float* out = (float*)d_out;

    const int N = in_sizes[0] / 256;
    const int E = in_sizes[1];
    const int NB = (N + 255) / 256;       // <= 256 (N <= 65536)
    const int total4 = N * 64;
    const int castB = (total4 + 1023) / 1024;
    const int countB = (E + 255) / 256;

    char* p = (char*)d_ws;
    auto alloc = [&](size_t bytes) { char* r = p; p += (bytes + 63) & ~63ull; return r; };
    u64_t* epair = (u64_t*)alloc((size_t)E * sizeof(u64_t));
    float* wsum = (float*)alloc(256 * sizeof(float));
    int* counts = (int*)alloc((size_t)N * CSTRIDE * sizeof(int));
    int* bsum = (int*)alloc(256 * sizeof(int));
    int* rowptr = (int*)alloc((size_t)(N + 1) * sizeof(int));
    int* posArr = (int*)alloc((size_t)E * sizeof(int));
    ushort_t* fni = (ushort_t*)alloc((size_t)N * 256 * sizeof(ushort_t));
    ushort_t* fhv = (ushort_t*)alloc((size_t)N * 256 * sizeof(ushort_t));
    ushort_t* fnj = (ushort_t*)alloc((size_t)N * 256 * sizeof(ushort_t));
    ushort_t* Abf = (ushort_t*)alloc((size_t)N * 256 * sizeof(ushort_t));
    ushort_t* BcatT = (ushort_t*)alloc((size_t)768 * 256 * sizeof(ushort_t));

    (void)hipMemsetAsync(counts, 0, (size_t)N * CSTRIDE * sizeof(int), stream);

    prep_kernel<<<castB + 768 + countB + 1, 256, 0, stream>>>(
        nfeats, Wni, Wnj, Wnode, Wfij, dst, Abf, BcatT, wsum, counts, posArr,
        castB, countB, total4, E);

    scan_block_sums<<<NB, 256, 0, stream>>>(counts, bsum, N);
    scan_final<<<NB, 256, 0, stream>>>(counts, bsum, rowptr, N, E);

    const int gX = (N + 127) / 128;
    const int gemmB = gX * 6;
    sg_fused<<<gemmB + countB, 256, 0, stream>>>(
        src, dst, reward, rowptr, posArr, epair, E, gemmB,
        Abf, BcatT, bias, fni, fhv, fnj, N, gX);

    node_fused<<<(N + 3) / 4, 256, 0, stream>>>(fni, fhv, fnj, rowptr, epair,
                                                wsum, attn, out, N);
}